// Round 5
// baseline (659.012 us; speedup 1.0000x reference)
//
#include <hip/hip_runtime.h>
#include <cmath>

namespace {

constexpr int XC = 64, XH = 128, XW = 128;
constexpr int NSEQ = 128;   // B(2) * 64 cubes
constexpr int TLEN = 1025;  // gt token + 1024
constexpr int LSEQ = 1024;
constexpr int NCH = 16;     // chunks per sequence (parallel scan)
constexpr int CHUNK = 65;   // 16*65 = 1040 >= 1025
constexpr int TT = 128;     // token tile for p1a/p1b
constexpr int NT = 9;       // ceil(1025/128)

__device__ __forceinline__ int xidx(int b, int c, int h, int w) {
    return ((b * XC + c) * XH + h) * XW + w;
}
__device__ __forceinline__ int oidx(int b, int cube, int c, int i, int j) {
    int h = cube * 2 + (i >> 3);
    int w = ((i & 7) << 4) | j;
    return xidx(b, c, h, w);
}
__device__ __forceinline__ float siluf(float v) { return v / (1.0f + __expf(-v)); }
__device__ __forceinline__ float softplusf(float v) {
    return v > 20.0f ? v : log1pf(__expf(v));
}

template <int MODE>
__device__ __forceinline__ float gather_val(const float* __restrict__ x,
                                            const float* __restrict__ s_gt,
                                            int t, int k, int b, int bi, int bj) {
    if (t == 0) return s_gt[k];
    int l = t - 1;
    if (MODE == 0) {
        int i2 = l >> 5, j2 = l & 31;
        int h = bi * 16 + (i2 >> 1), w = bj * 16 + (j2 >> 1);
        int coff = ((i2 & 1) << 1) | (j2 & 1);
        return x[xidx(b, k * 4 + coff, h, w)];
    } else if (MODE == 1) {
        int c = l >> 4, j = l & 15;
        return x[xidx(b, c, bi * 16 + k, bj * 16 + j)];
    } else {
        int c = l >> 4, i = l & 15;
        return x[xidx(b, c, bi * 16 + i, bj * 16 + k)];
    }
}

// ======= phase 1a (tiled): gather + LN + in-proj, coalesced stores ==========
template <int MODE>
__global__ __launch_bounds__(256) void k_p1a(
    const float* __restrict__ x, const float* __restrict__ gt,
    const float* __restrict__ lng, const float* __restrict__ lnb,
    const float* __restrict__ in_w,  // (64,16)
    float* __restrict__ XI,          // (NSEQ,TLEN,32)
    float* __restrict__ Zb)          // (NSEQ,TLEN,32)
{
    const int n = blockIdx.x / NT, tile = blockIdx.x % NT;
    const int t0 = tile * TT;
    const int ntk = min(TT, TLEN - t0);
    const int b = n >> 6, cube = n & 63, bi = cube >> 3, bj = cube & 7;
    const int tid = threadIdx.x;

    __shared__ float s_v[TT][17];
    __shared__ float s_wT[16][64];
    __shared__ float s_g[16], s_bb[16], s_gt[16];

    for (int i = tid; i < 64 * 16; i += 256) s_wT[i & 15][i >> 4] = in_w[i];
    if (tid < 16) { s_g[tid] = lng[tid]; s_bb[tid] = lnb[tid]; s_gt[tid] = gt[tid]; }
    __syncthreads();

    for (int it = tid; it < ntk * 16; it += 256) {
        int tl = it >> 4, k = it & 15;
        s_v[tl][k] = gather_val<MODE>(x, s_gt, t0 + tl, k, b, bi, bj);
    }
    __syncthreads();

    if (tid < ntk) {
        float v[16], mu = 0.f;
#pragma unroll
        for (int k = 0; k < 16; k++) { v[k] = s_v[tid][k]; mu += v[k]; }
        mu *= (1.f / 16.f);
        float var = 0.f;
#pragma unroll
        for (int k = 0; k < 16; k++) { float d = v[k] - mu; var += d * d; }
        float inv = rsqrtf(var * (1.f / 16.f) + 1e-5f);
#pragma unroll
        for (int k = 0; k < 16; k++) s_v[tid][k] = (v[k] - mu) * inv * s_g[k] + s_bb[k];
    }
    __syncthreads();

    // in-proj: it = token*64 + oc  -> contiguous wave stores
    for (int it = tid; it < ntk * 64; it += 256) {
        int tl = it >> 6, oc = it & 63;
        float acc = 0.f;
#pragma unroll
        for (int k = 0; k < 16; k++) acc += s_v[tl][k] * s_wT[k][oc];
        size_t base = ((size_t)n * TLEN + t0 + tl) * 32;
        if (oc < 32) XI[base + oc] = acc;
        else         Zb[base + oc - 32] = acc;
    }
}

// ======= phase 1b v2: token-per-thread, xc in regs, broadcast xp ============
__global__ __launch_bounds__(128) void k_p1b(
    const float* __restrict__ XI,
    const float* __restrict__ conv_w,  // (32,4)
    const float* __restrict__ conv_b,  // (32)
    const float* __restrict__ xproj_w, // (33,32)
    const float* __restrict__ dt_w,    // (32,1)
    const float* __restrict__ dt_b,    // (32)
    float* __restrict__ sc)            // (NSEQ,TLEN,96): xc[32] dt[32] B[16] C[16]
{
    const int n = blockIdx.x / NT, tile = blockIdx.x % NT;
    const int t0 = tile * TT;
    const int ntk = min(TT, TLEN - t0);
    const int tid = threadIdx.x;

    __shared__ float s_xi[TT + 3][33];  // stride 33: conflict-free col reads
    __shared__ float s_out[TT][97];     // stride 97: conflict-free row writes
    __shared__ float s_xp[33][33];
    __shared__ float s_cw[128], s_cb[32], s_dw[32], s_db[32];

    for (int i = tid; i < 33 * 32; i += 128) s_xp[i >> 5][i & 31] = xproj_w[i];
    s_cw[tid] = conv_w[tid];
    if (tid < 32) {
        s_cb[tid] = conv_b[tid];
        s_dw[tid] = dt_w[tid];
        s_db[tid] = dt_b[tid];
    }
    // stage xi tile + 3-token halo (coalesced b32)
    for (int it = tid; it < (ntk + 3) * 32; it += 128) {
        int tl = it >> 5, cc = it & 31;
        int t = t0 - 3 + tl;
        s_xi[tl][cc] = (t < 0) ? 0.f : XI[((size_t)n * TLEN + t) * 32 + cc];
    }
    __syncthreads();

    if (tid < ntk) {
        const int j = tid;
        float xc[32];
#pragma unroll
        for (int cc = 0; cc < 32; cc++) {
            float acc = 0.f;
#pragma unroll
            for (int k = 0; k < 4; k++) acc += s_cw[cc * 4 + k] * s_xi[j + k][cc];
            xc[cc] = siluf(acc + s_cb[cc]);
        }
        float dt0 = 0.f;
#pragma unroll
        for (int cc = 0; cc < 32; cc++) dt0 += xc[cc] * s_xp[0][cc];
#pragma unroll
        for (int cc = 0; cc < 32; cc++) s_out[j][cc] = xc[cc];
#pragma unroll
        for (int d = 0; d < 32; d++) s_out[j][32 + d] = softplusf(dt0 * s_dw[d] + s_db[d]);
#pragma unroll
        for (int r = 1; r <= 32; r++) {  // r=1..16 -> B, r=17..32 -> C
            float acc = 0.f;
#pragma unroll
            for (int cc = 0; cc < 32; cc++) acc += xc[cc] * s_xp[r][cc];
            s_out[j][63 + r] = acc;
        }
    }
    __syncthreads();

    // coalesced copy-out
    float* scb = sc + ((size_t)n * TLEN + t0) * 96;
    for (int it = tid; it < ntk * 96; it += 128) {
        int j = it / 96, e = it - j * 96;
        scb[it] = s_out[j][e];
    }
}

// -------- phase 2a: per-chunk scan summaries; thread = (d, s-group of 4) ----
__global__ __launch_bounds__(128) void k_scan1(const float* __restrict__ sc,
                                               const float* __restrict__ A_log,
                                               float* __restrict__ Psum,
                                               float* __restrict__ Fsum)
{
    int n = blockIdx.x >> 4;
    int c = blockIdx.x & (NCH - 1);
    int t0 = c * CHUNK;
    int nt = min(CHUNK, TLEN - t0);
    __shared__ __align__(16) float s_sc[CHUNK * 96];
    const float* src = sc + ((size_t)n * TLEN + t0) * 96;
    int nv4 = nt * 24;
    for (int i = threadIdx.x; i < nv4; i += 128)
        ((float4*)s_sc)[i] = ((const float4*)src)[i];
    int tid = threadIdx.x, d = tid >> 2, sg = tid & 3;
    float4 Av = *(const float4*)&A_log[d * 16 + sg * 4];
    float A0 = -__expf(Av.x), A1 = -__expf(Av.y), A2 = -__expf(Av.z), A3 = -__expf(Av.w);
    __syncthreads();
    float h0 = 0.f, h1 = 0.f, h2 = 0.f, h3 = 0.f;
    float P0 = 1.f, P1 = 1.f, P2 = 1.f, P3 = 1.f;
    for (int t = 0; t < nt; t++) {
        const float* p = s_sc + t * 96;
        float dt = p[32 + d], xc = p[d];
        float4 Bv = *(const float4*)&p[64 + sg * 4];
        float a0 = __expf(dt * A0); h0 = a0 * h0 + dt * Bv.x * xc; P0 *= a0;
        float a1 = __expf(dt * A1); h1 = a1 * h1 + dt * Bv.y * xc; P1 *= a1;
        float a2 = __expf(dt * A2); h2 = a2 * h2 + dt * Bv.z * xc; P2 *= a2;
        float a3 = __expf(dt * A3); h3 = a3 * h3 + dt * Bv.w * xc; P3 *= a3;
    }
    size_t base = ((size_t)n * NCH + c) * 512 + d * 16 + sg * 4;
    *(float4*)&Psum[base] = make_float4(P0, P1, P2, P3);
    *(float4*)&Fsum[base] = make_float4(h0, h1, h2, h3);
}

// -------- phase 2b: combine chunk summaries -> incoming state per chunk -----
__global__ __launch_bounds__(512) void k_comb(const float* __restrict__ Psum,
                                              const float* __restrict__ Fsum,
                                              float* __restrict__ Hin)
{
    int n = blockIdx.x, tid = threadIdx.x;
    const float* pb = Psum + (size_t)n * NCH * 512;
    const float* fb = Fsum + (size_t)n * NCH * 512;
    float* hb = Hin + (size_t)n * NCH * 512;
    float H = 0.f;
#pragma unroll
    for (int c = 0; c < NCH; c++) {
        float P = pb[(size_t)c * 512 + tid];
        float F = fb[(size_t)c * 512 + tid];
        hb[(size_t)c * 512 + tid] = H;
        H = F + P * H;
    }
}

// -------- phase 2c: per-chunk scan pass 2, thread = (d, s-group of 4) -------
__global__ __launch_bounds__(128) void k_scan2(const float* __restrict__ sc,
                                               const float* __restrict__ A_log,
                                               const float* __restrict__ Dp,
                                               const float* __restrict__ Hin,
                                               float* __restrict__ yc)  // (NSEQ,TLEN,32)
{
    int n = blockIdx.x >> 4;
    int c = blockIdx.x & (NCH - 1);
    int t0 = c * CHUNK;
    int nt = min(CHUNK, TLEN - t0);
    __shared__ __align__(16) float s_sc[CHUNK * 96];
    __shared__ __align__(16) float s_y[CHUNK * 32];
    const float* src = sc + ((size_t)n * TLEN + t0) * 96;
    int nv4 = nt * 24;
    for (int i = threadIdx.x; i < nv4; i += 128)
        ((float4*)s_sc)[i] = ((const float4*)src)[i];
    int tid = threadIdx.x, d = tid >> 2, sg = tid & 3;
    float4 Av = *(const float4*)&A_log[d * 16 + sg * 4];
    float A0 = -__expf(Av.x), A1 = -__expf(Av.y), A2 = -__expf(Av.z), A3 = -__expf(Av.w);
    float Dd = Dp[d];
    float4 Hv = *(const float4*)&Hin[((size_t)n * NCH + c) * 512 + d * 16 + sg * 4];
    float h0 = Hv.x, h1 = Hv.y, h2 = Hv.z, h3 = Hv.w;
    __syncthreads();
    for (int t = 0; t < nt; t++) {
        const float* p = s_sc + t * 96;
        float dt = p[32 + d], xc = p[d];
        float4 Bv = *(const float4*)&p[64 + sg * 4];
        float4 Cv = *(const float4*)&p[80 + sg * 4];
        float a0 = __expf(dt * A0); h0 = a0 * h0 + dt * Bv.x * xc;
        float a1 = __expf(dt * A1); h1 = a1 * h1 + dt * Bv.y * xc;
        float a2 = __expf(dt * A2); h2 = a2 * h2 + dt * Bv.z * xc;
        float a3 = __expf(dt * A3); h3 = a3 * h3 + dt * Bv.w * xc;
        float pp = h0 * Cv.x + h1 * Cv.y + h2 * Cv.z + h3 * Cv.w;
        pp += __shfl_xor(pp, 1);
        pp += __shfl_xor(pp, 2);
        if (sg == 0) s_y[t * 32 + d] = pp + Dd * xc;
    }
    __syncthreads();
    float* yb = yc + ((size_t)n * TLEN + t0) * 32;
    int ny4 = nt * 8;
    for (int i = threadIdx.x; i < ny4; i += 128)
        ((float4*)yb)[i] = ((const float4*)s_y)[i];
}

// ---------------- phase 3: gate + out-proj + scatter ------------------------
template <int MODE>
__global__ void k_p3(const float* __restrict__ yc, const float* __restrict__ Zb,
                     const float* __restrict__ out_w,  // (16,32)
                     float* __restrict__ out)
{
    __shared__ float s_w[16 * 32];
    for (int i = threadIdx.x; i < 512; i += blockDim.x) s_w[i] = out_w[i];
    __syncthreads();
    int tid = blockIdx.x * blockDim.x + threadIdx.x;
    if (tid >= NSEQ * LSEQ) return;
    int n = tid >> 10, l = tid & 1023, t = l + 1;
    const float* y = yc + ((size_t)n * TLEN + t) * 32;
    const float* z = Zb + ((size_t)n * TLEN + t) * 32;
    float yv[32];
#pragma unroll
    for (int c = 0; c < 32; c++) yv[c] = y[c] * siluf(z[c]);
    float o[16];
#pragma unroll
    for (int j = 0; j < 16; j++) {
        float acc = 0.f;
#pragma unroll
        for (int c = 0; c < 32; c++) acc += yv[c] * s_w[j * 32 + c];
        o[j] = acc * (1.0f / 3.0f);
    }
    int b = n >> 6, cube = n & 63;
    if (MODE == 0) {
        int i2 = l >> 5, j2 = l & 31;
        int io = i2 >> 1, jo = j2 >> 1;
        int coff = ((i2 & 1) << 1) | (j2 & 1);
#pragma unroll
        for (int j = 0; j < 16; j++) out[oidx(b, cube, j * 4 + coff, io, jo)] = o[j];
    } else if (MODE == 1) {
        int c = l >> 4, jj = l & 15;
#pragma unroll
        for (int j = 0; j < 16; j++) out[oidx(b, cube, c, j, jj)] += o[j];
    } else {
        int c = l >> 4, ii = l & 15;
#pragma unroll
        for (int j = 0; j < 16; j++) out[oidx(b, cube, c, ii, j)] += o[j];
    }
}

}  // namespace

extern "C" void kernel_launch(void* const* d_in, const int* in_sizes, int n_in,
                              void* d_out, int out_size, void* d_ws, size_t ws_size,
                              hipStream_t stream) {
    const float* x   = (const float*)d_in[0];
    const float* gt1 = (const float*)d_in[1];
    const float* gt2 = (const float*)d_in[2];
    const float* ln1g = (const float*)d_in[3];
    const float* ln1b = (const float*)d_in[4];
    const float* ln2g = (const float*)d_in[5];
    const float* ln2b = (const float*)d_in[6];
    const float* m[2][9];
    for (int mi = 0; mi < 2; mi++)
        for (int k = 0; k < 9; k++) m[mi][k] = (const float*)d_in[7 + mi * 9 + k];
    float* out = (float*)d_out;

    float* ws = (float*)d_ws;
    float* XI = ws;                               // 128*1025*32 (16.8 MB)
    float* ZB = XI + (size_t)NSEQ * TLEN * 32;    // 16.8 MB
    float* SC = ZB + (size_t)NSEQ * TLEN * 32;    // 128*1025*96 (50.4 MB)
    float* YC = SC + (size_t)NSEQ * TLEN * 96;    // 16.8 MB
    float* PS = YC + (size_t)NSEQ * TLEN * 32;    // 4.2 MB
    float* FS = PS + (size_t)NSEQ * NCH * 512;    // 4.2 MB
    float* HI = FS + (size_t)NSEQ * NCH * 512;    // 4.2 MB

    dim3 gtile(NSEQ * NT);
    dim3 gscan(NSEQ * NCH);
    dim3 grd3((NSEQ * LSEQ + 255) / 256);

    for (int mode = 0; mode < 3; mode++) {
        int pi = (mode == 0) ? 0 : 1;
        const float* gt = (mode == 0) ? gt1 : gt2;
        const float* lg = (mode == 0) ? ln1g : ln2g;
        const float* lb = (mode == 0) ? ln1b : ln2b;
        const float* const* P = m[pi];
        // P: 0 in_w, 1 conv_w, 2 conv_b, 3 xproj_w, 4 dt_w, 5 dt_b, 6 A_log, 7 D, 8 out_w
        if (mode == 0)      k_p1a<0><<<gtile, dim3(256), 0, stream>>>(x, gt, lg, lb, P[0], XI, ZB);
        else if (mode == 1) k_p1a<1><<<gtile, dim3(256), 0, stream>>>(x, gt, lg, lb, P[0], XI, ZB);
        else                k_p1a<2><<<gtile, dim3(256), 0, stream>>>(x, gt, lg, lb, P[0], XI, ZB);
        k_p1b<<<gtile, dim3(128), 0, stream>>>(XI, P[1], P[2], P[3], P[4], P[5], SC);
        k_scan1<<<gscan, dim3(128), 0, stream>>>(SC, P[6], PS, FS);
        k_comb<<<dim3(NSEQ), dim3(512), 0, stream>>>(PS, FS, HI);
        k_scan2<<<gscan, dim3(128), 0, stream>>>(SC, P[6], P[7], HI, YC);
        if (mode == 0)      k_p3<0><<<grd3, dim3(256), 0, stream>>>(YC, ZB, P[8], out);
        else if (mode == 1) k_p3<1><<<grd3, dim3(256), 0, stream>>>(YC, ZB, P[8], out);
        else                k_p3<2><<<grd3, dim3(256), 0, stream>>>(YC, ZB, P[8], out);
    }
}

// Round 6
// 586.207 us; speedup vs baseline: 1.1242x; 1.1242x over previous
//
#include <hip/hip_runtime.h>
#include <cmath>

namespace {

constexpr int XC = 64, XH = 128, XW = 128;
constexpr int NSEQ = 128;   // B(2) * 64 cubes
constexpr int TLEN = 1025;  // gt token + 1024
constexpr int LSEQ = 1024;
constexpr int NCH = 16;     // chunks per sequence (parallel scan)
constexpr int CHUNK = 65;   // 16*65 = 1040 >= 1025
constexpr int TT = 128;     // token tile for fused p1
constexpr int NT = 9;       // ceil(1025/128)

__device__ __forceinline__ int xidx(int b, int c, int h, int w) {
    return ((b * XC + c) * XH + h) * XW + w;
}
__device__ __forceinline__ int oidx(int b, int cube, int c, int i, int j) {
    int h = cube * 2 + (i >> 3);
    int w = ((i & 7) << 4) | j;
    return xidx(b, c, h, w);
}
__device__ __forceinline__ float siluf(float v) { return v / (1.0f + __expf(-v)); }
__device__ __forceinline__ float softplusf(float v) {
    return v > 20.0f ? v : log1pf(__expf(v));
}

template <int MODE>
__device__ __forceinline__ float gather_val(const float* __restrict__ x,
                                            const float* __restrict__ s_gt,
                                            int t, int k, int b, int bi, int bj) {
    if (t == 0) return s_gt[k];
    int l = t - 1;
    if (MODE == 0) {
        int i2 = l >> 5, j2 = l & 31;
        int h = bi * 16 + (i2 >> 1), w = bj * 16 + (j2 >> 1);
        int coff = ((i2 & 1) << 1) | (j2 & 1);
        return x[xidx(b, k * 4 + coff, h, w)];
    } else if (MODE == 1) {
        int c = l >> 4, j = l & 15;
        return x[xidx(b, c, bi * 16 + k, bj * 16 + j)];
    } else {
        int c = l >> 4, i = l & 15;
        return x[xidx(b, c, bi * 16 + i, bj * 16 + k)];
    }
}

// ==== fused phase 1: gather + LN + in-proj + conv + x-proj (halo recompute) ==
// Element-per-thread in every phase; all stores coalesced.
template <int MODE>
__global__ __launch_bounds__(256) void k_p1(
    const float* __restrict__ x, const float* __restrict__ gt,
    const float* __restrict__ lng, const float* __restrict__ lnb,
    const float* __restrict__ in_w,    // (64,16)
    const float* __restrict__ conv_w,  // (32,4)
    const float* __restrict__ conv_b,  // (32)
    const float* __restrict__ xproj_w, // (33,32)
    const float* __restrict__ dt_w,    // (32,1)
    const float* __restrict__ dt_b,    // (32)
    float* __restrict__ Zb,            // (NSEQ,TLEN,32)
    float* __restrict__ sc)            // (NSEQ,TLEN,96): xc[32] dt[32] B[16] C[16]
{
    const int n = blockIdx.x / NT, tile = blockIdx.x % NT;
    const int t0 = tile * TT;
    const int ntk = min(TT, TLEN - t0);
    const int nth = ntk + 3;  // with 3-token halo
    const int b = n >> 6, cube = n & 63, bi = cube >> 3, bj = cube & 7;
    const int tid = threadIdx.x;

    __shared__ float s_xi[TT + 3][33];
    __shared__ float s_pool[TT * 33];  // s_v (stride 17) then s_xc (stride 33)
    __shared__ float s_dt0[TT];
    __shared__ float s_wT[16][64];     // in_w transposed
    __shared__ float s_xp[33][33];
    __shared__ float s_cw[128], s_cb[32], s_dw[32], s_db[32];
    __shared__ float s_g[16], s_bb[16], s_gt[16];
    float (*s_v)[17] = (float(*)[17])s_pool;   // [TT+3][17] = 2227 <= 4224
    float (*s_xc)[33] = (float(*)[33])s_pool;  // [TT][33], disjoint lifetime

    for (int i = tid; i < 64 * 16; i += 256) s_wT[i & 15][i >> 4] = in_w[i];
    for (int i = tid; i < 33 * 32; i += 256) s_xp[i >> 5][i & 31] = xproj_w[i];
    if (tid < 128) s_cw[tid] = conv_w[tid];
    if (tid < 32) { s_cb[tid] = conv_b[tid]; s_dw[tid] = dt_w[tid]; s_db[tid] = dt_b[tid]; }
    if (tid < 16) { s_g[tid] = lng[tid]; s_bb[tid] = lnb[tid]; s_gt[tid] = gt[tid]; }
    __syncthreads();

    // gather raw tokens incl. halo
    for (int it = tid; it < nth * 16; it += 256) {
        int tl = it >> 4, k = it & 15;
        int t = t0 - 3 + tl;
        s_v[tl][k] = (t < 0) ? 0.f : gather_val<MODE>(x, s_gt, t, k, b, bi, bj);
    }
    __syncthreads();

    // layernorm per token
    for (int tl = tid; tl < nth; tl += 256) {
        int t = t0 - 3 + tl;
        if (t < 0) continue;
        float v[16], mu = 0.f;
#pragma unroll
        for (int k = 0; k < 16; k++) { v[k] = s_v[tl][k]; mu += v[k]; }
        mu *= (1.f / 16.f);
        float var = 0.f;
#pragma unroll
        for (int k = 0; k < 16; k++) { float d = v[k] - mu; var += d * d; }
        float inv = rsqrtf(var * (1.f / 16.f) + 1e-5f);
#pragma unroll
        for (int k = 0; k < 16; k++) s_v[tl][k] = (v[k] - mu) * inv * s_g[k] + s_bb[k];
    }
    __syncthreads();

    // in-proj xi half (all tokens incl. halo) -> s_xi
    for (int it = tid; it < nth * 32; it += 256) {
        int tl = it >> 5, oc = it & 31;
        int t = t0 - 3 + tl;
        float acc = 0.f;
        if (t >= 0) {
#pragma unroll
            for (int k = 0; k < 16; k++) acc += s_v[tl][k] * s_wT[k][oc];
        }
        s_xi[tl][oc] = acc;
    }
    // in-proj z half (main tokens only) -> ZB, coalesced
    {
        float* zb = Zb + ((size_t)n * TLEN + t0) * 32;
        for (int it = tid; it < ntk * 32; it += 256) {
            int tl = it >> 5, oc = it & 31;
            float acc = 0.f;
#pragma unroll
            for (int k = 0; k < 16; k++) acc += s_v[tl + 3][k] * s_wT[k][32 + oc];
            zb[it] = acc;
        }
    }
    __syncthreads();  // s_v dead from here; pool becomes s_xc

    // conv4 + silu
    for (int it = tid; it < ntk * 32; it += 256) {
        int j = it >> 5, cc = it & 31;
        float acc = 0.f;
#pragma unroll
        for (int k = 0; k < 4; k++) acc += s_cw[cc * 4 + k] * s_xi[j + k][cc];
        s_xc[j][cc] = siluf(acc + s_cb[cc]);
    }
    __syncthreads();

    // dt0 per token
    if (tid < ntk) {
        float acc = 0.f;
#pragma unroll
        for (int cc = 0; cc < 32; cc++) acc += s_xc[tid][cc] * s_xp[0][cc];
        s_dt0[tid] = acc;
    }
    __syncthreads();

    // emit SC: it = token*96 + e -> contiguous wave stores
    float* scb = sc + ((size_t)n * TLEN + t0) * 96;
    for (int it = tid; it < ntk * 96; it += 256) {
        int j = it / 96, e = it - j * 96;
        float val;
        if (e < 32) {
            val = s_xc[j][e];
        } else if (e < 64) {
            int d = e - 32;
            val = softplusf(s_dt0[j] * s_dw[d] + s_db[d]);
        } else {
            int r = (e < 80) ? (1 + e - 64) : (17 + e - 80);
            float acc = 0.f;
#pragma unroll
            for (int cc = 0; cc < 32; cc++) acc += s_xc[j][cc] * s_xp[r][cc];
            val = acc;
        }
        scb[it] = val;
    }
}

// -------- phase 2a: per-chunk scan summaries; thread = (d, s-group of 4) ----
__global__ __launch_bounds__(128) void k_scan1(const float* __restrict__ sc,
                                               const float* __restrict__ A_log,
                                               float* __restrict__ Psum,
                                               float* __restrict__ Fsum)
{
    int n = blockIdx.x >> 4;
    int c = blockIdx.x & (NCH - 1);
    int t0 = c * CHUNK;
    int nt = min(CHUNK, TLEN - t0);
    __shared__ __align__(16) float s_sc[CHUNK * 96];
    const float* src = sc + ((size_t)n * TLEN + t0) * 96;
    int nv4 = nt * 24;
    for (int i = threadIdx.x; i < nv4; i += 128)
        ((float4*)s_sc)[i] = ((const float4*)src)[i];
    int tid = threadIdx.x, d = tid >> 2, sg = tid & 3;
    float4 Av = *(const float4*)&A_log[d * 16 + sg * 4];
    float A0 = -__expf(Av.x), A1 = -__expf(Av.y), A2 = -__expf(Av.z), A3 = -__expf(Av.w);
    __syncthreads();
    float h0 = 0.f, h1 = 0.f, h2 = 0.f, h3 = 0.f;
    float P0 = 1.f, P1 = 1.f, P2 = 1.f, P3 = 1.f;
    for (int t = 0; t < nt; t++) {
        const float* p = s_sc + t * 96;
        float dt = p[32 + d], xc = p[d];
        float4 Bv = *(const float4*)&p[64 + sg * 4];
        float a0 = __expf(dt * A0); h0 = a0 * h0 + dt * Bv.x * xc; P0 *= a0;
        float a1 = __expf(dt * A1); h1 = a1 * h1 + dt * Bv.y * xc; P1 *= a1;
        float a2 = __expf(dt * A2); h2 = a2 * h2 + dt * Bv.z * xc; P2 *= a2;
        float a3 = __expf(dt * A3); h3 = a3 * h3 + dt * Bv.w * xc; P3 *= a3;
    }
    size_t base = ((size_t)n * NCH + c) * 512 + d * 16 + sg * 4;
    *(float4*)&Psum[base] = make_float4(P0, P1, P2, P3);
    *(float4*)&Fsum[base] = make_float4(h0, h1, h2, h3);
}

// -------- phase 2b: combine chunk summaries -> incoming state per chunk -----
__global__ __launch_bounds__(512) void k_comb(const float* __restrict__ Psum,
                                              const float* __restrict__ Fsum,
                                              float* __restrict__ Hin)
{
    int n = blockIdx.x, tid = threadIdx.x;
    const float* pb = Psum + (size_t)n * NCH * 512;
    const float* fb = Fsum + (size_t)n * NCH * 512;
    float* hb = Hin + (size_t)n * NCH * 512;
    float H = 0.f;
#pragma unroll
    for (int c = 0; c < NCH; c++) {
        float P = pb[(size_t)c * 512 + tid];
        float F = fb[(size_t)c * 512 + tid];
        hb[(size_t)c * 512 + tid] = H;
        H = F + P * H;
    }
}

// -------- phase 2c: per-chunk scan pass 2, thread = (d, s-group of 4) -------
__global__ __launch_bounds__(128) void k_scan2(const float* __restrict__ sc,
                                               const float* __restrict__ A_log,
                                               const float* __restrict__ Dp,
                                               const float* __restrict__ Hin,
                                               float* __restrict__ yc)  // (NSEQ,TLEN,32)
{
    int n = blockIdx.x >> 4;
    int c = blockIdx.x & (NCH - 1);
    int t0 = c * CHUNK;
    int nt = min(CHUNK, TLEN - t0);
    __shared__ __align__(16) float s_sc[CHUNK * 96];
    __shared__ __align__(16) float s_y[CHUNK * 32];
    const float* src = sc + ((size_t)n * TLEN + t0) * 96;
    int nv4 = nt * 24;
    for (int i = threadIdx.x; i < nv4; i += 128)
        ((float4*)s_sc)[i] = ((const float4*)src)[i];
    int tid = threadIdx.x, d = tid >> 2, sg = tid & 3;
    float4 Av = *(const float4*)&A_log[d * 16 + sg * 4];
    float A0 = -__expf(Av.x), A1 = -__expf(Av.y), A2 = -__expf(Av.z), A3 = -__expf(Av.w);
    float Dd = Dp[d];
    float4 Hv = *(const float4*)&Hin[((size_t)n * NCH + c) * 512 + d * 16 + sg * 4];
    float h0 = Hv.x, h1 = Hv.y, h2 = Hv.z, h3 = Hv.w;
    __syncthreads();
    for (int t = 0; t < nt; t++) {
        const float* p = s_sc + t * 96;
        float dt = p[32 + d], xc = p[d];
        float4 Bv = *(const float4*)&p[64 + sg * 4];
        float4 Cv = *(const float4*)&p[80 + sg * 4];
        float a0 = __expf(dt * A0); h0 = a0 * h0 + dt * Bv.x * xc;
        float a1 = __expf(dt * A1); h1 = a1 * h1 + dt * Bv.y * xc;
        float a2 = __expf(dt * A2); h2 = a2 * h2 + dt * Bv.z * xc;
        float a3 = __expf(dt * A3); h3 = a3 * h3 + dt * Bv.w * xc;
        float pp = h0 * Cv.x + h1 * Cv.y + h2 * Cv.z + h3 * Cv.w;
        pp += __shfl_xor(pp, 1);
        pp += __shfl_xor(pp, 2);
        if (sg == 0) s_y[t * 32 + d] = pp + Dd * xc;
    }
    __syncthreads();
    float* yb = yc + ((size_t)n * TLEN + t0) * 32;
    int ny4 = nt * 8;
    for (int i = threadIdx.x; i < ny4; i += 128)
        ((float4*)yb)[i] = ((const float4*)s_y)[i];
}

// ---------------- phase 3: gate + out-proj + scatter ------------------------
template <int MODE>
__global__ void k_p3(const float* __restrict__ yc, const float* __restrict__ Zb,
                     const float* __restrict__ out_w,  // (16,32)
                     float* __restrict__ out)
{
    __shared__ float s_w[16 * 32];
    for (int i = threadIdx.x; i < 512; i += blockDim.x) s_w[i] = out_w[i];
    __syncthreads();
    int tid = blockIdx.x * blockDim.x + threadIdx.x;
    if (tid >= NSEQ * LSEQ) return;
    int n = tid >> 10, l = tid & 1023, t = l + 1;
    const float* y = yc + ((size_t)n * TLEN + t) * 32;
    const float* z = Zb + ((size_t)n * TLEN + t) * 32;
    float yv[32];
#pragma unroll
    for (int c = 0; c < 32; c++) yv[c] = y[c] * siluf(z[c]);
    float o[16];
#pragma unroll
    for (int j = 0; j < 16; j++) {
        float acc = 0.f;
#pragma unroll
        for (int c = 0; c < 32; c++) acc += yv[c] * s_w[j * 32 + c];
        o[j] = acc * (1.0f / 3.0f);
    }
    int b = n >> 6, cube = n & 63;
    if (MODE == 0) {
        int i2 = l >> 5, j2 = l & 31;
        int io = i2 >> 1, jo = j2 >> 1;
        int coff = ((i2 & 1) << 1) | (j2 & 1);
#pragma unroll
        for (int j = 0; j < 16; j++) out[oidx(b, cube, j * 4 + coff, io, jo)] = o[j];
    } else if (MODE == 1) {
        int c = l >> 4, jj = l & 15;
#pragma unroll
        for (int j = 0; j < 16; j++) out[oidx(b, cube, c, j, jj)] += o[j];
    } else {
        int c = l >> 4, ii = l & 15;
#pragma unroll
        for (int j = 0; j < 16; j++) out[oidx(b, cube, c, ii, j)] += o[j];
    }
}

}  // namespace

extern "C" void kernel_launch(void* const* d_in, const int* in_sizes, int n_in,
                              void* d_out, int out_size, void* d_ws, size_t ws_size,
                              hipStream_t stream) {
    const float* x   = (const float*)d_in[0];
    const float* gt1 = (const float*)d_in[1];
    const float* gt2 = (const float*)d_in[2];
    const float* ln1g = (const float*)d_in[3];
    const float* ln1b = (const float*)d_in[4];
    const float* ln2g = (const float*)d_in[5];
    const float* ln2b = (const float*)d_in[6];
    const float* m[2][9];
    for (int mi = 0; mi < 2; mi++)
        for (int k = 0; k < 9; k++) m[mi][k] = (const float*)d_in[7 + mi * 9 + k];
    float* out = (float*)d_out;

    float* ws = (float*)d_ws;
    float* ZB = ws;                               // 128*1025*32 (16.8 MB)
    float* SC = ZB + (size_t)NSEQ * TLEN * 32;    // 128*1025*96 (50.4 MB)
    float* YC = SC + (size_t)NSEQ * TLEN * 96;    // 16.8 MB
    float* PS = YC + (size_t)NSEQ * TLEN * 32;    // 4.2 MB
    float* FS = PS + (size_t)NSEQ * NCH * 512;    // 4.2 MB
    float* HI = FS + (size_t)NSEQ * NCH * 512;    // 4.2 MB

    dim3 gtile(NSEQ * NT);
    dim3 gscan(NSEQ * NCH);
    dim3 grd3((NSEQ * LSEQ + 255) / 256);

    for (int mode = 0; mode < 3; mode++) {
        int pi = (mode == 0) ? 0 : 1;
        const float* gt = (mode == 0) ? gt1 : gt2;
        const float* lg = (mode == 0) ? ln1g : ln2g;
        const float* lb = (mode == 0) ? ln1b : ln2b;
        const float* const* P = m[pi];
        // P: 0 in_w, 1 conv_w, 2 conv_b, 3 xproj_w, 4 dt_w, 5 dt_b, 6 A_log, 7 D, 8 out_w
        if (mode == 0)
            k_p1<0><<<gtile, dim3(256), 0, stream>>>(x, gt, lg, lb, P[0], P[1], P[2], P[3], P[4], P[5], ZB, SC);
        else if (mode == 1)
            k_p1<1><<<gtile, dim3(256), 0, stream>>>(x, gt, lg, lb, P[0], P[1], P[2], P[3], P[4], P[5], ZB, SC);
        else
            k_p1<2><<<gtile, dim3(256), 0, stream>>>(x, gt, lg, lb, P[0], P[1], P[2], P[3], P[4], P[5], ZB, SC);
        k_scan1<<<gscan, dim3(128), 0, stream>>>(SC, P[6], PS, FS);
        k_comb<<<dim3(NSEQ), dim3(512), 0, stream>>>(PS, FS, HI);
        k_scan2<<<gscan, dim3(128), 0, stream>>>(SC, P[6], P[7], HI, YC);
        if (mode == 0)      k_p3<0><<<grd3, dim3(256), 0, stream>>>(YC, ZB, P[8], out);
        else if (mode == 1) k_p3<1><<<grd3, dim3(256), 0, stream>>>(YC, ZB, P[8], out);
        else                k_p3<2><<<grd3, dim3(256), 0, stream>>>(YC, ZB, P[8], out);
    }
}

// Round 7
// 431.873 us; speedup vs baseline: 1.5259x; 1.3574x over previous
//
#include <hip/hip_runtime.h>
#include <cmath>

namespace {

constexpr int XC = 64, XH = 128, XW = 128;
constexpr int NSEQ = 128;   // B(2) * 64 cubes
constexpr int TLEN = 1025;  // gt token + 1024
constexpr int LSEQ = 1024;
constexpr int NCH = 16;     // chunks per sequence (parallel scan)
constexpr int CHUNK = 65;   // 16*65 = 1040 >= 1025
constexpr int TT = 128;     // token tile for fused p1
constexpr int NT = 9;       // ceil(1025/128)

__device__ __forceinline__ int xidx(int b, int c, int h, int w) {
    return ((b * XC + c) * XH + h) * XW + w;
}
__device__ __forceinline__ int oidx(int b, int cube, int c, int i, int j) {
    int h = cube * 2 + (i >> 3);
    int w = ((i & 7) << 4) | j;
    return xidx(b, c, h, w);
}
__device__ __forceinline__ float siluf(float v) { return v / (1.0f + __expf(-v)); }
__device__ __forceinline__ float softplusf(float v) {
    return v > 20.0f ? v : log1pf(__expf(v));
}

template <int MODE>
__device__ __forceinline__ float gather_val(const float* __restrict__ x,
                                            const float* __restrict__ s_gt,
                                            int t, int k, int b, int bi, int bj) {
    if (t == 0) return s_gt[k];
    int l = t - 1;
    if (MODE == 0) {
        int i2 = l >> 5, j2 = l & 31;
        int h = bi * 16 + (i2 >> 1), w = bj * 16 + (j2 >> 1);
        int coff = ((i2 & 1) << 1) | (j2 & 1);
        return x[xidx(b, k * 4 + coff, h, w)];
    } else if (MODE == 1) {
        int c = l >> 4, j = l & 15;
        return x[xidx(b, c, bi * 16 + k, bj * 16 + j)];
    } else {
        int c = l >> 4, i = l & 15;
        return x[xidx(b, c, bi * 16 + i, bj * 16 + k)];
    }
}

// ==== fused phase 1: gather+LN+in-proj+conv+x-proj, register-tiled GEMMs ====
template <int MODE>
__global__ __launch_bounds__(256) void k_p1(
    const float* __restrict__ x, const float* __restrict__ gt,
    const float* __restrict__ lng, const float* __restrict__ lnb,
    const float* __restrict__ in_w,    // (64,16)
    const float* __restrict__ conv_w,  // (32,4)
    const float* __restrict__ conv_b,  // (32)
    const float* __restrict__ xproj_w, // (33,32)
    const float* __restrict__ dt_w,    // (32,1)
    const float* __restrict__ dt_b,    // (32)
    float* __restrict__ Zb,            // (NSEQ,TLEN,32)
    float* __restrict__ sc)            // (NSEQ,TLEN,96): xc[32] dt[32] B[16] C[16]
{
    const int n = blockIdx.x / NT, tile = blockIdx.x % NT;
    const int t0 = tile * TT;
    const int ntk = min(TT, TLEN - t0);
    const int nth = ntk + 3;  // with 3-token front halo
    const int b = n >> 6, cube = n & 63, bi = cube >> 3, bj = cube & 7;
    const int tid = threadIdx.x;

    // s_v [132][17] (2244 f) overlaid on s_xc [128][37] (4736 f): disjoint life
    __shared__ __align__(16) float s_pool[128 * 37];
    float (*s_v)[17]  = (float(*)[17])s_pool;
    float (*s_xc)[37] = (float(*)[37])s_pool;
    __shared__ __align__(16) float s_xi[132][36];
    __shared__ __align__(16) float s_wT[16][64];   // s_wT[k][oc] = in_w[oc][k]
    __shared__ __align__(16) float s_xpT[32][36];  // s_xpT[cc][q] = xproj_w[q+1][cc]
    __shared__ float s_xp0[32];
    __shared__ float s_cw[128], s_cb[32], s_dw[32], s_db[32];
    __shared__ float s_g[16], s_bb[16], s_gt[16];
    __shared__ float s_dt0[128];

    for (int i = tid; i < 64 * 16; i += 256) s_wT[i & 15][i >> 4] = in_w[i];
    for (int i = tid; i < 33 * 32; i += 256) {
        int r = i >> 5, cc = i & 31;
        float v = xproj_w[i];
        if (r == 0) s_xp0[cc] = v;
        else s_xpT[cc][r - 1] = v;
    }
    if (tid < 128) s_cw[tid] = conv_w[tid];
    if (tid < 32) { s_cb[tid] = conv_b[tid]; s_dw[tid] = dt_w[tid]; s_db[tid] = dt_b[tid]; }
    if (tid < 16) { s_g[tid] = lng[tid]; s_bb[tid] = lnb[tid]; s_gt[tid] = gt[tid]; }
    __syncthreads();

    // ---- gather + LN, token-per-thread, registers only
    if (tid < nth) {
        int t = t0 - 3 + tid;
        float v[16];
        if (t < 0) {
#pragma unroll
            for (int k = 0; k < 16; k++) v[k] = 0.f;
        } else {
#pragma unroll
            for (int k = 0; k < 16; k++) v[k] = gather_val<MODE>(x, s_gt, t, k, b, bi, bj);
            float mu = 0.f;
#pragma unroll
            for (int k = 0; k < 16; k++) mu += v[k];
            mu *= (1.f / 16.f);
            float var = 0.f;
#pragma unroll
            for (int k = 0; k < 16; k++) { float d = v[k] - mu; var += d * d; }
            float inv = rsqrtf(var * (1.f / 16.f) + 1e-5f);
#pragma unroll
            for (int k = 0; k < 16; k++) v[k] = (v[k] - mu) * inv * s_g[k] + s_bb[k];
        }
#pragma unroll
        for (int k = 0; k < 16; k++) s_v[tid][k] = v[k];
    }
    __syncthreads();

    // ---- in-proj, 4-token x 4-oc register tiles (og<8 -> xi LDS, og>=8 -> z)
    {
        const int ntt = (nth + 3) >> 2;
        for (int tl0 = tid; tl0 < ntt * 16; tl0 += 256) {
            int tt = tl0 >> 4, og = tl0 & 15;
            int oc = og * 4;
            float acc[4][4] = {{0.f}};
#pragma unroll
            for (int k = 0; k < 16; k++) {
                float4 wv = *(const float4*)&s_wT[k][oc];
                float a0 = s_v[4 * tt + 0][k];
                float a1 = s_v[4 * tt + 1][k];
                float a2 = s_v[4 * tt + 2][k];
                float a3 = s_v[4 * tt + 3][k];
                acc[0][0] += a0 * wv.x; acc[0][1] += a0 * wv.y; acc[0][2] += a0 * wv.z; acc[0][3] += a0 * wv.w;
                acc[1][0] += a1 * wv.x; acc[1][1] += a1 * wv.y; acc[1][2] += a1 * wv.z; acc[1][3] += a1 * wv.w;
                acc[2][0] += a2 * wv.x; acc[2][1] += a2 * wv.y; acc[2][2] += a2 * wv.z; acc[2][3] += a2 * wv.w;
                acc[3][0] += a3 * wv.x; acc[3][1] += a3 * wv.y; acc[3][2] += a3 * wv.z; acc[3][3] += a3 * wv.w;
            }
#pragma unroll
            for (int i = 0; i < 4; i++) {
                int tl = 4 * tt + i;
                if (tl >= nth) break;
                if (og < 8) {
                    *(float4*)&s_xi[tl][oc] =
                        make_float4(acc[i][0], acc[i][1], acc[i][2], acc[i][3]);
                } else if (tl >= 3) {
                    *(float4*)&Zb[((size_t)n * TLEN + t0 + tl - 3) * 32 + (oc - 32)] =
                        make_float4(acc[i][0], acc[i][1], acc[i][2], acc[i][3]);
                }
            }
        }
    }
    __syncthreads();  // s_v dead; pool becomes s_xc

    // ---- conv4 + silu: thread = (cc, token-group), weights in registers
    {
        int cc = tid & 31, jg = tid >> 5;
        float c0 = s_cw[cc * 4 + 0], c1 = s_cw[cc * 4 + 1];
        float c2 = s_cw[cc * 4 + 2], c3 = s_cw[cc * 4 + 3];
        float cb = s_cb[cc];
        for (int j = jg; j < ntk; j += 8) {
            float acc = 0.f;
            acc += c0 * s_xi[j + 0][cc];
            acc += c1 * s_xi[j + 1][cc];
            acc += c2 * s_xi[j + 2][cc];
            acc += c3 * s_xi[j + 3][cc];
            s_xc[j][cc] = siluf(acc + cb);
        }
    }
    __syncthreads();

    // ---- x-proj B/C rows, 4-token x 4-q register tile (exactly 1 per thread)
    {
        int qt = tid & 7, tt = tid >> 3;
        if (4 * tt < ntk) {
            float acc[4][4] = {{0.f}};
#pragma unroll
            for (int cc = 0; cc < 32; cc++) {
                float4 wv = *(const float4*)&s_xpT[cc][4 * qt];
                float a0 = s_xc[4 * tt + 0][cc];
                float a1 = s_xc[4 * tt + 1][cc];
                float a2 = s_xc[4 * tt + 2][cc];
                float a3 = s_xc[4 * tt + 3][cc];
                acc[0][0] += a0 * wv.x; acc[0][1] += a0 * wv.y; acc[0][2] += a0 * wv.z; acc[0][3] += a0 * wv.w;
                acc[1][0] += a1 * wv.x; acc[1][1] += a1 * wv.y; acc[1][2] += a1 * wv.z; acc[1][3] += a1 * wv.w;
                acc[2][0] += a2 * wv.x; acc[2][1] += a2 * wv.y; acc[2][2] += a2 * wv.z; acc[2][3] += a2 * wv.w;
                acc[3][0] += a3 * wv.x; acc[3][1] += a3 * wv.y; acc[3][2] += a3 * wv.z; acc[3][3] += a3 * wv.w;
            }
#pragma unroll
            for (int i = 0; i < 4; i++) {
                int j = 4 * tt + i;
                if (j < ntk)
                    *(float4*)&sc[((size_t)n * TLEN + t0 + j) * 96 + 64 + 4 * qt] =
                        make_float4(acc[i][0], acc[i][1], acc[i][2], acc[i][3]);
            }
        }
        // dt0 per token (reads only s_xc / s_xp0)
        if (tid < ntk) {
            float acc = 0.f;
#pragma unroll
            for (int cc = 0; cc < 32; cc++) acc += s_xc[tid][cc] * s_xp0[cc];
            s_dt0[tid] = acc;
        }
    }
    __syncthreads();

    // ---- dt block + xc block emits (coalesced stores)
    {
        float* scb = sc + ((size_t)n * TLEN + t0) * 96;
        for (int it = tid; it < ntk * 32; it += 256) {
            int j = it >> 5, d = it & 31;
            scb[j * 96 + 32 + d] = softplusf(s_dt0[j] * s_dw[d] + s_db[d]);
        }
        for (int it = tid; it < ntk * 32; it += 256) {
            int j = it >> 5, cc = it & 31;
            scb[j * 96 + cc] = s_xc[j][cc];
        }
    }
}

// -------- phase 2a: per-chunk scan summaries; thread = (d, s-group of 4) ----
__global__ __launch_bounds__(128) void k_scan1(const float* __restrict__ sc,
                                               const float* __restrict__ A_log,
                                               float* __restrict__ Psum,
                                               float* __restrict__ Fsum)
{
    int n = blockIdx.x >> 4;
    int c = blockIdx.x & (NCH - 1);
    int t0 = c * CHUNK;
    int nt = min(CHUNK, TLEN - t0);
    __shared__ __align__(16) float s_sc[CHUNK * 96];
    const float* src = sc + ((size_t)n * TLEN + t0) * 96;
    int nv4 = nt * 24;
    for (int i = threadIdx.x; i < nv4; i += 128)
        ((float4*)s_sc)[i] = ((const float4*)src)[i];
    int tid = threadIdx.x, d = tid >> 2, sg = tid & 3;
    float4 Av = *(const float4*)&A_log[d * 16 + sg * 4];
    float A0 = -__expf(Av.x), A1 = -__expf(Av.y), A2 = -__expf(Av.z), A3 = -__expf(Av.w);
    __syncthreads();
    float h0 = 0.f, h1 = 0.f, h2 = 0.f, h3 = 0.f;
    float P0 = 1.f, P1 = 1.f, P2 = 1.f, P3 = 1.f;
    for (int t = 0; t < nt; t++) {
        const float* p = s_sc + t * 96;
        float dt = p[32 + d], xc = p[d];
        float4 Bv = *(const float4*)&p[64 + sg * 4];
        float a0 = __expf(dt * A0); h0 = a0 * h0 + dt * Bv.x * xc; P0 *= a0;
        float a1 = __expf(dt * A1); h1 = a1 * h1 + dt * Bv.y * xc; P1 *= a1;
        float a2 = __expf(dt * A2); h2 = a2 * h2 + dt * Bv.z * xc; P2 *= a2;
        float a3 = __expf(dt * A3); h3 = a3 * h3 + dt * Bv.w * xc; P3 *= a3;
    }
    size_t base = ((size_t)n * NCH + c) * 512 + d * 16 + sg * 4;
    *(float4*)&Psum[base] = make_float4(P0, P1, P2, P3);
    *(float4*)&Fsum[base] = make_float4(h0, h1, h2, h3);
}

// -------- phase 2b: combine chunk summaries -> incoming state per chunk -----
__global__ __launch_bounds__(512) void k_comb(const float* __restrict__ Psum,
                                              const float* __restrict__ Fsum,
                                              float* __restrict__ Hin)
{
    int n = blockIdx.x, tid = threadIdx.x;
    const float* pb = Psum + (size_t)n * NCH * 512;
    const float* fb = Fsum + (size_t)n * NCH * 512;
    float* hb = Hin + (size_t)n * NCH * 512;
    float H = 0.f;
#pragma unroll
    for (int c = 0; c < NCH; c++) {
        float P = pb[(size_t)c * 512 + tid];
        float F = fb[(size_t)c * 512 + tid];
        hb[(size_t)c * 512 + tid] = H;
        H = F + P * H;
    }
}

// -------- phase 2c: per-chunk scan pass 2, thread = (d, s-group of 4) -------
__global__ __launch_bounds__(128) void k_scan2(const float* __restrict__ sc,
                                               const float* __restrict__ A_log,
                                               const float* __restrict__ Dp,
                                               const float* __restrict__ Hin,
                                               float* __restrict__ yc)  // (NSEQ,TLEN,32)
{
    int n = blockIdx.x >> 4;
    int c = blockIdx.x & (NCH - 1);
    int t0 = c * CHUNK;
    int nt = min(CHUNK, TLEN - t0);
    __shared__ __align__(16) float s_sc[CHUNK * 96];
    __shared__ __align__(16) float s_y[CHUNK * 32];
    const float* src = sc + ((size_t)n * TLEN + t0) * 96;
    int nv4 = nt * 24;
    for (int i = threadIdx.x; i < nv4; i += 128)
        ((float4*)s_sc)[i] = ((const float4*)src)[i];
    int tid = threadIdx.x, d = tid >> 2, sg = tid & 3;
    float4 Av = *(const float4*)&A_log[d * 16 + sg * 4];
    float A0 = -__expf(Av.x), A1 = -__expf(Av.y), A2 = -__expf(Av.z), A3 = -__expf(Av.w);
    float Dd = Dp[d];
    float4 Hv = *(const float4*)&Hin[((size_t)n * NCH + c) * 512 + d * 16 + sg * 4];
    float h0 = Hv.x, h1 = Hv.y, h2 = Hv.z, h3 = Hv.w;
    __syncthreads();
    for (int t = 0; t < nt; t++) {
        const float* p = s_sc + t * 96;
        float dt = p[32 + d], xc = p[d];
        float4 Bv = *(const float4*)&p[64 + sg * 4];
        float4 Cv = *(const float4*)&p[80 + sg * 4];
        float a0 = __expf(dt * A0); h0 = a0 * h0 + dt * Bv.x * xc;
        float a1 = __expf(dt * A1); h1 = a1 * h1 + dt * Bv.y * xc;
        float a2 = __expf(dt * A2); h2 = a2 * h2 + dt * Bv.z * xc;
        float a3 = __expf(dt * A3); h3 = a3 * h3 + dt * Bv.w * xc;
        float pp = h0 * Cv.x + h1 * Cv.y + h2 * Cv.z + h3 * Cv.w;
        pp += __shfl_xor(pp, 1);
        pp += __shfl_xor(pp, 2);
        if (sg == 0) s_y[t * 32 + d] = pp + Dd * xc;
    }
    __syncthreads();
    float* yb = yc + ((size_t)n * TLEN + t0) * 32;
    int ny4 = nt * 8;
    for (int i = threadIdx.x; i < ny4; i += 128)
        ((float4*)yb)[i] = ((const float4*)s_y)[i];
}

// ---------------- phase 3: gate + out-proj + scatter ------------------------
template <int MODE>
__global__ void k_p3(const float* __restrict__ yc, const float* __restrict__ Zb,
                     const float* __restrict__ out_w,  // (16,32)
                     float* __restrict__ out)
{
    __shared__ float s_w[16 * 32];
    for (int i = threadIdx.x; i < 512; i += blockDim.x) s_w[i] = out_w[i];
    __syncthreads();
    int tid = blockIdx.x * blockDim.x + threadIdx.x;
    if (tid >= NSEQ * LSEQ) return;
    int n = tid >> 10, l = tid & 1023, t = l + 1;
    const float* y = yc + ((size_t)n * TLEN + t) * 32;
    const float* z = Zb + ((size_t)n * TLEN + t) * 32;
    float yv[32];
#pragma unroll
    for (int c = 0; c < 32; c++) yv[c] = y[c] * siluf(z[c]);
    float o[16];
#pragma unroll
    for (int j = 0; j < 16; j++) {
        float acc = 0.f;
#pragma unroll
        for (int c = 0; c < 32; c++) acc += yv[c] * s_w[j * 32 + c];
        o[j] = acc * (1.0f / 3.0f);
    }
    int b = n >> 6, cube = n & 63;
    if (MODE == 0) {
        int i2 = l >> 5, j2 = l & 31;
        int io = i2 >> 1, jo = j2 >> 1;
        int coff = ((i2 & 1) << 1) | (j2 & 1);
#pragma unroll
        for (int j = 0; j < 16; j++) out[oidx(b, cube, j * 4 + coff, io, jo)] = o[j];
    } else if (MODE == 1) {
        int c = l >> 4, jj = l & 15;
#pragma unroll
        for (int j = 0; j < 16; j++) out[oidx(b, cube, c, j, jj)] += o[j];
    } else {
        int c = l >> 4, ii = l & 15;
#pragma unroll
        for (int j = 0; j < 16; j++) out[oidx(b, cube, c, ii, j)] += o[j];
    }
}

}  // namespace

extern "C" void kernel_launch(void* const* d_in, const int* in_sizes, int n_in,
                              void* d_out, int out_size, void* d_ws, size_t ws_size,
                              hipStream_t stream) {
    const float* x   = (const float*)d_in[0];
    const float* gt1 = (const float*)d_in[1];
    const float* gt2 = (const float*)d_in[2];
    const float* ln1g = (const float*)d_in[3];
    const float* ln1b = (const float*)d_in[4];
    const float* ln2g = (const float*)d_in[5];
    const float* ln2b = (const float*)d_in[6];
    const float* m[2][9];
    for (int mi = 0; mi < 2; mi++)
        for (int k = 0; k < 9; k++) m[mi][k] = (const float*)d_in[7 + mi * 9 + k];
    float* out = (float*)d_out;

    float* ws = (float*)d_ws;
    float* ZB = ws;                               // 128*1025*32 (16.8 MB)
    float* SC = ZB + (size_t)NSEQ * TLEN * 32;    // 128*1025*96 (50.4 MB)
    float* YC = SC + (size_t)NSEQ * TLEN * 96;    // 16.8 MB
    float* PS = YC + (size_t)NSEQ * TLEN * 32;    // 4.2 MB
    float* FS = PS + (size_t)NSEQ * NCH * 512;    // 4.2 MB
    float* HI = FS + (size_t)NSEQ * NCH * 512;    // 4.2 MB

    dim3 gtile(NSEQ * NT);
    dim3 gscan(NSEQ * NCH);
    dim3 grd3((NSEQ * LSEQ + 255) / 256);

    for (int mode = 0; mode < 3; mode++) {
        int pi = (mode == 0) ? 0 : 1;
        const float* gt = (mode == 0) ? gt1 : gt2;
        const float* lg = (mode == 0) ? ln1g : ln2g;
        const float* lb = (mode == 0) ? ln1b : ln2b;
        const float* const* P = m[pi];
        // P: 0 in_w, 1 conv_w, 2 conv_b, 3 xproj_w, 4 dt_w, 5 dt_b, 6 A_log, 7 D, 8 out_w
        if (mode == 0)
            k_p1<0><<<gtile, dim3(256), 0, stream>>>(x, gt, lg, lb, P[0], P[1], P[2], P[3], P[4], P[5], ZB, SC);
        else if (mode == 1)
            k_p1<1><<<gtile, dim3(256), 0, stream>>>(x, gt, lg, lb, P[0], P[1], P[2], P[3], P[4], P[5], ZB, SC);
        else
            k_p1<2><<<gtile, dim3(256), 0, stream>>>(x, gt, lg, lb, P[0], P[1], P[2], P[3], P[4], P[5], ZB, SC);
        k_scan1<<<gscan, dim3(128), 0, stream>>>(SC, P[6], PS, FS);
        k_comb<<<dim3(NSEQ), dim3(512), 0, stream>>>(PS, FS, HI);
        k_scan2<<<gscan, dim3(128), 0, stream>>>(SC, P[6], P[7], HI, YC);
        if (mode == 0)      k_p3<0><<<grd3, dim3(256), 0, stream>>>(YC, ZB, P[8], out);
        else if (mode == 1) k_p3<1><<<grd3, dim3(256), 0, stream>>>(YC, ZB, P[8], out);
        else                k_p3<2><<<grd3, dim3(256), 0, stream>>>(YC, ZB, P[8], out);
    }
}